// Round 7
// baseline (229.147 us; speedup 1.0000x reference)
//
#include <hip/hip_runtime.h>
#include <hip/hip_bf16.h>
#include <stdint.h>

typedef unsigned short u16;
typedef __attribute__((ext_vector_type(8))) short short8;
typedef __attribute__((ext_vector_type(4))) float f32x4;

#define B_DIM 4096
#define D_DIM 1024
#define H_DIM 1024
#define K_DIM 2048   // D + H
#define N_DIM 4096   // 4H
#define LN_EPS 1e-5f

// ---------- helpers ----------
__device__ __forceinline__ u16 f2bf(float f) {
    union { float f; uint32_t u; } v; v.f = f;
    uint32_t u = v.u;
    uint32_t r = (u + 0x7FFFu + ((u >> 16) & 1u)) >> 16;  // RNE
    return (u16)r;
}
__device__ __forceinline__ float bf2f(u16 h) {
    union { uint32_t u; float f; } v; v.u = ((uint32_t)h) << 16;
    return v.f;
}
__device__ __forceinline__ void gld16(const u16* g, u16* l) {
    __builtin_amdgcn_global_load_lds(
        (const __attribute__((address_space(1))) void*)g,
        (__attribute__((address_space(3))) void*)l,
        16, 0, 0);
}
__device__ __forceinline__ float sigm(float x) { return 1.0f / (1.0f + __expf(-x)); }
__device__ __forceinline__ float tanh_fast(float x) { return 1.0f - 2.0f / (__expf(2.0f * x) + 1.0f); }

// ---------- kernel 1: fused prep ----------
__global__ __launch_bounds__(256) void prep(const float* __restrict__ x,
                                            const float* __restrict__ h,
                                            const float* __restrict__ Wx,
                                            const float* __restrict__ Wh,
                                            u16* __restrict__ A,
                                            u16* __restrict__ Bt) {
    __shared__ u16 tile[64 * 64];
    const int t = threadIdx.x;
    if (blockIdx.x < 4096) {
        int id = blockIdx.x * 256 + t;
        int row = id >> 8;
        int col = (id & 255) * 8;
        const float* src = (col < D_DIM) ? (x + (size_t)row * D_DIM + col)
                                         : (h + (size_t)row * H_DIM + (col - D_DIM));
        float4 v0 = ((const float4*)src)[0];
        float4 v1 = ((const float4*)src)[1];
        union { u16 us[8]; uint4 u; } p;
        p.us[0] = f2bf(v0.x); p.us[1] = f2bf(v0.y); p.us[2] = f2bf(v0.z); p.us[3] = f2bf(v0.w);
        p.us[4] = f2bf(v1.x); p.us[5] = f2bf(v1.y); p.us[6] = f2bf(v1.z); p.us[7] = f2bf(v1.w);
        *(uint4*)(A + (size_t)id * 8) = p.u;
    } else {
        const int v = blockIdx.x - 4096;       // 0..2047 = 64 x 32
        const int n0 = (v & 63) * 64;
        const int k0 = (v >> 6) * 64;
        const int kl  = t >> 4;                // 0..15
        const int nl4 = (t & 15) * 4;          // 0..60
#pragma unroll
        for (int it = 0; it < 4; ++it) {
            const int klocal = kl + it * 16;
            const int k = k0 + klocal;
            const float* src = (k < D_DIM) ? (Wx + (size_t)k * N_DIM)
                                           : (Wh + (size_t)(k - D_DIM) * N_DIM);
            float4 w = *(const float4*)(src + n0 + nl4);
            union { u16 us[4]; uint2 u; } p;
            p.us[0] = f2bf(w.x); p.us[1] = f2bf(w.y); p.us[2] = f2bf(w.z); p.us[3] = f2bf(w.w);
            const int swz = 8 * ((klocal >> 4) & 3);
            *(uint2*)(tile + klocal * 64 + (nl4 ^ swz)) = p.u;
        }
        __syncthreads();
        const int nl = t >> 2;
        const int kp = (t & 3) * 16;
        const int swz = 8 * (t & 3);
        union { u16 us[16]; uint4 q[2]; } o;
#pragma unroll
        for (int i = 0; i < 16; ++i)
            o.us[i] = tile[(kp + i) * 64 + (nl ^ swz)];
        u16* dst = Bt + (size_t)(n0 + nl) * K_DIM + k0 + kp;
        *(uint4*)dst = o.q[0];
        *(uint4*)(dst + 8) = o.q[1];
    }
}

// ---------- kernel 2: GEMM a = A @ Bt^T + bias -> bf16 [4096][4096] ----------
// 128x128 block, 2 waves, each wave 128x64 via 8x4 of 16x16x32 MFMA, BK=32,
// double-buffered LDS (32 KB total -> 4 blocks/CU, 8 waves/CU TLP), 1 barrier
// per iter. LDS geometry = round-2's MEASURED-zero-conflict class: 64 B rows
// (32 u16), 4 16B-blocks/row, stored block s at row r holds global k-block
// (s - (r>>1)) & 3; fragment read s = (g + (lr>>1)) & 3. Within every 8-lane
// LDS granule the accesses cover all 8 bank quads (4 s x 2 row-parity).
__global__ __launch_bounds__(128, 2) void gemm_bf16(const u16* __restrict__ A,   // [4096][2048]
                                                    const u16* __restrict__ Bt,  // [4096][2048]
                                                    const float* __restrict__ bias,
                                                    u16* __restrict__ C) {       // [4096][4096]
    __shared__ u16 As[2][4096];   // [buf][row*32 + s*8], 128 rows
    __shared__ u16 Bs[2][4096];
    const int tid = threadIdx.x;
    const int wave = tid >> 6, lane = tid & 63;
    const int m0 = blockIdx.y * 128;
    const int n0 = blockIdx.x * 128;
    const int wn = wave * 64;

    f32x4 acc[8][4] = {};

    // staging: chunk = 1 KB = 16 rows x 32 u16; 8 chunks per matrix; wave w
    // takes chunks w*4..w*4+3. Lane l -> row ch*16 + (l>>2), stored block l&3
    // holds global block perm = ((l&3) - (l>>3)) & 3  (row>>1 mod 4 == l>>3).
    const int perm = ((lane & 3) - (lane >> 3)) & 3;
    const int vofs = (lane >> 2) * K_DIM + perm * 8;   // per-lane global offset

    // fragment read: lr = lane&15 (row in 16-tile), g = lane>>4 (k-block)
    const int lr = lane & 15;
    const int g  = lane >> 4;
    const int koff = ((g + (lr >> 1)) & 3) * 8;

    for (int it = 0; it <= K_DIM / 32; ++it) {
        if (it < K_DIM / 32) {
            const int kt = it * 32;
            const int buf = it & 1;
#pragma unroll
            for (int q = 0; q < 4; ++q) {
                const int ch = wave * 4 + q;
                gld16(A  + (size_t)(m0 + ch * 16) * K_DIM + kt + vofs, &As[buf][ch * 512]);
                gld16(Bt + (size_t)(n0 + ch * 16) * K_DIM + kt + vofs, &Bs[buf][ch * 512]);
            }
        }
        if (it == 0) { __syncthreads(); continue; }

        const int cbuf = (it - 1) & 1;
        short8 bF[4];
#pragma unroll
        for (int j = 0; j < 4; ++j)
            bF[j] = *(const short8*)(&Bs[cbuf][(wn + j * 16 + lr) * 32 + koff]);
#pragma unroll
        for (int i = 0; i < 8; ++i) {
            short8 aF = *(const short8*)(&As[cbuf][(i * 16 + lr) * 32 + koff]);
#pragma unroll
            for (int j = 0; j < 4; ++j)
                acc[i][j] = __builtin_amdgcn_mfma_f32_16x16x32_bf16(aF, bF[j], acc[i][j], 0, 0, 0);
        }
        __syncthreads();   // prefetch for `it` drains here, after full compute phase
    }

    // epilogue: 16x16 C/D layout col=lane&15, row=(lane>>4)*4+reg (m89/m91)
#pragma unroll
    for (int j = 0; j < 4; ++j) {
        const int c = n0 + wn + j * 16 + lr;
        const float bb = bias[c];
#pragma unroll
        for (int i = 0; i < 8; ++i) {
            const int r0 = m0 + i * 16 + g * 4;
#pragma unroll
            for (int r = 0; r < 4; ++r)
                C[(size_t)(r0 + r) * N_DIM + c] = f2bf(acc[i][j][r] + bb);
        }
    }
}

// ---------- kernel 3: LayerNorm + gates + cell update (single pass over aT) ----------
__global__ __launch_bounds__(256) void ln_lstm(const u16* __restrict__ aT,     // [4096][4096] bf16
                                               const float* __restrict__ pc,   // prev_c
                                               const float* __restrict__ gamma,
                                               const float* __restrict__ beta,
                                               float* __restrict__ out) {      // [h | c]
    const int row = blockIdx.x;
    const int t = threadIdx.x;
    const u16* ar = aT + (size_t)row * N_DIM;
    const int j0 = t * 4;

    union U2 { uint2 u; u16 us[4]; };
    U2 g4[4];
#pragma unroll
    for (int s = 0; s < 4; ++s) g4[s].u = *(const uint2*)(ar + s * H_DIM + j0);

    float sum = 0.f, ssq = 0.f;
#pragma unroll
    for (int s = 0; s < 4; ++s)
#pragma unroll
        for (int e = 0; e < 4; ++e) { float v = bf2f(g4[s].us[e]); sum += v; ssq += v * v; }

#pragma unroll
    for (int off = 32; off > 0; off >>= 1) {
        sum += __shfl_down(sum, off, 64);
        ssq += __shfl_down(ssq, off, 64);
    }
    __shared__ float red[8];
    if ((t & 63) == 0) { red[t >> 6] = sum; red[4 + (t >> 6)] = ssq; }
    __syncthreads();
    const float ts = red[0] + red[1] + red[2] + red[3];
    const float tq = red[4] + red[5] + red[6] + red[7];
    const float mu = ts * (1.0f / N_DIM);
    const float var = fmaxf(tq * (1.0f / N_DIM) - mu * mu, 0.0f);
    const float rs = rsqrtf(var + LN_EPS);

    float vi[4], vf[4], vo[4], vg[4];
    auto gate = [&](int s, float* v) {
        const int off = s * H_DIM;
        float4 gm = *(const float4*)(gamma + off + j0);
        float4 bt = *(const float4*)(beta + off + j0);
        v[0] = (bf2f(g4[s].us[0]) - mu) * rs * gm.x + bt.x;
        v[1] = (bf2f(g4[s].us[1]) - mu) * rs * gm.y + bt.y;
        v[2] = (bf2f(g4[s].us[2]) - mu) * rs * gm.z + bt.z;
        v[3] = (bf2f(g4[s].us[3]) - mu) * rs * gm.w + bt.w;
    };
    gate(0, vi); gate(1, vf); gate(2, vo); gate(3, vg);

    float4 c4 = *(const float4*)(pc + (size_t)row * H_DIM + j0);
    float cin[4] = {c4.x, c4.y, c4.z, c4.w};
    float nh[4], nc[4];
#pragma unroll
    for (int r = 0; r < 4; ++r) {
        float ig = sigm(vi[r]);
        float fg = sigm(vf[r]);
        float og = sigm(vo[r]);
        float gg = tanh_fast(vg[r]);
        nc[r] = fg * cin[r] + ig * gg;
        nh[r] = og * tanh_fast(nc[r]);
    }
    float4 h4 = {nh[0], nh[1], nh[2], nh[3]};
    float4 c4o = {nc[0], nc[1], nc[2], nc[3]};
    *(float4*)(out + (size_t)row * H_DIM + j0) = h4;
    *(float4*)(out + (size_t)B_DIM * H_DIM + (size_t)row * H_DIM + j0) = c4o;
}

// ---------- launch ----------
extern "C" void kernel_launch(void* const* d_in, const int* in_sizes, int n_in,
                              void* d_out, int out_size, void* d_ws, size_t ws_size,
                              hipStream_t stream) {
    const float* x  = (const float*)d_in[0];
    const float* ph = (const float*)d_in[1];
    const float* pc = (const float*)d_in[2];
    const float* Wx = (const float*)d_in[3];
    const float* Wh = (const float*)d_in[4];
    const float* b  = (const float*)d_in[5];
    const float* gm = (const float*)d_in[6];
    const float* bt = (const float*)d_in[7];
    float* out = (float*)d_out;

    char* ws = (char*)d_ws;
    u16* Abf = (u16*)ws;                               // 16 MiB: [4096][2048] bf16
    u16* Btb = (u16*)(ws + (size_t)16 * 1024 * 1024);  // 16 MiB: [4096][2048] bf16
    u16* aT  = (u16*)(ws + (size_t)32 * 1024 * 1024);  // 32 MiB: [4096][4096] bf16

    prep<<<dim3(4096 + 2048), dim3(256), 0, stream>>>(x, ph, Wx, Wh, Abf, Btb);
    gemm_bf16<<<dim3(32, 32), dim3(128), 0, stream>>>(Abf, Btb, b, aT);
    ln_lstm<<<dim3(4096), dim3(256), 0, stream>>>(aT, pc, gm, bt, out);
}